// Round 3
// baseline (9816.136 us; speedup 1.0000x reference)
//
#include <hip/hip_runtime.h>

#define DIVUP(a,b) (((a)+(b)-1)/(b))

// ---------------------------------------------------------------------------
// anchor broadcast: out[b][c][y][x] = anchor_crop[c][y][x]
__global__ void bcast_anchor_kernel(const float* __restrict__ a, float* __restrict__ out) {
    int i = blockIdx.x * 256 + threadIdx.x;   // over 3*127*127 = 48387
    int b = blockIdx.y;
    if (i < 48387) out[b * 48387 + i] = a[i];
}

// ---------------------------------------------------------------------------
// conv K=4 stride=2 VALID + ReLU.  w: (Cout,Cin,4,4).  grid: (tiles(HW), Cout, B)
__global__ void conv4s2_relu_kernel(const float* __restrict__ in, const float* __restrict__ w,
                                    const float* __restrict__ bias, float* __restrict__ out,
                                    int Cin, int Hin, int Win, int Hout, int Wout)
{
    const int oc = blockIdx.y, b = blockIdx.z, Cout = gridDim.y;
    __shared__ float sw[1024];                 // Cin<=64 -> Cin*16<=1024
    const int nw = Cin * 16;
    for (int i = threadIdx.x; i < nw; i += blockDim.x) sw[i] = w[oc * nw + i];
    __syncthreads();
    const int p = blockIdx.x * blockDim.x + threadIdx.x;
    if (p >= Hout * Wout) return;
    const int oy = p / Wout, ox = p - oy * Wout;
    const float* ip = in + ((b * Cin) * Hin + 2 * oy) * Win + 2 * ox;
    float acc = bias[oc];
    for (int ic = 0; ic < Cin; ++ic) {
        const float* r  = ip + ic * Hin * Win;
        const float* wc = sw + ic * 16;
        #pragma unroll
        for (int ky = 0; ky < 4; ++ky) {
            const float* rr = r + ky * Win;
            acc = fmaf(rr[0], wc[4*ky+0], acc);
            acc = fmaf(rr[1], wc[4*ky+1], acc);
            acc = fmaf(rr[2], wc[4*ky+2], acc);
            acc = fmaf(rr[3], wc[4*ky+3], acc);
        }
    }
    out[((b * Cout + oc) * Hout + oy) * Wout + ox] = fmaxf(acc, 0.0f);
}

// ---------------------------------------------------------------------------
// fused VAE head: mu = h*mw+mb, logvar = h*lw+lb, z = mu + eps*exp(0.5*logvar)
__global__ void vae_head_kernel(const float* __restrict__ h, const float* __restrict__ mw,
                                const float* __restrict__ mb, const float* __restrict__ lw,
                                const float* __restrict__ lb, const float* __restrict__ eps,
                                float* __restrict__ mu_out, float* __restrict__ lv_out,
                                float* __restrict__ z_out)
{
    const int idx = blockIdx.x * 256 + threadIdx.x;   // over 64*32*196
    if (idx >= 64 * 32 * 196) return;
    const int p  = idx % 196;
    const int oc = (idx / 196) % 32;
    const int b  = idx / (196 * 32);
    const float* hb = h + (b * 64) * 196 + p;
    float am = mb[oc], al = lb[oc];
    for (int ic = 0; ic < 64; ++ic) {
        float hv = hb[ic * 196];
        am = fmaf(hv, mw[oc * 64 + ic], am);
        al = fmaf(hv, lw[oc * 64 + ic], al);
    }
    mu_out[idx] = am;
    lv_out[idx] = al;
    z_out[idx]  = fmaf(eps[idx], expf(0.5f * al), am);
}

// ---------------------------------------------------------------------------
// 1x1 conv + ReLU.  w: (Cout,Cin)
__global__ void conv1x1_relu_kernel(const float* __restrict__ in, const float* __restrict__ w,
                                    const float* __restrict__ bias, float* __restrict__ out,
                                    int Cin, int Cout, int HW, int total)
{
    const int idx = blockIdx.x * 256 + threadIdx.x;
    if (idx >= total) return;
    const int p  = idx % HW;
    const int oc = (idx / HW) % Cout;
    const int b  = idx / (HW * Cout);
    const float* ib = in + (b * Cin) * HW + p;
    float acc = bias[oc];
    for (int ic = 0; ic < Cin; ++ic) acc = fmaf(ib[ic * HW], w[oc * Cin + ic], acc);
    out[idx] = fmaxf(acc, 0.0f);
}

// ---------------------------------------------------------------------------
// transposed conv K=4 stride=2 VALID + ReLU (JAX conv_transpose: no kernel flip,
// pad_a = K-1 = 3 -> input tap iy = (oy+ky-3)/2 when even & in range).
// w: (Cout,Cin,4,4).  grid: (tiles(HW), Cout, B)
__global__ void deconv4s2_relu_kernel(const float* __restrict__ in, const float* __restrict__ w,
                                      const float* __restrict__ bias, float* __restrict__ out,
                                      int Cin, int Hin, int Win, int Hout, int Wout)
{
    const int oc = blockIdx.y, b = blockIdx.z, Cout = gridDim.y;
    __shared__ float sw[1024];
    const int nw = Cin * 16;
    for (int i = threadIdx.x; i < nw; i += blockDim.x) sw[i] = w[oc * nw + i];
    __syncthreads();
    const int p = blockIdx.x * blockDim.x + threadIdx.x;
    if (p >= Hout * Wout) return;
    const int oy = p / Wout, ox = p - oy * Wout;
    int iys[2], kys[2], niy = 0;
    int ixs[2], kxs[2], nix = 0;
    #pragma unroll
    for (int k = 0; k < 4; ++k) {
        int t = oy + k - 3;
        if (t >= 0 && !(t & 1) && (t >> 1) < Hin) { iys[niy] = t >> 1; kys[niy] = k; ++niy; }
        int u = ox + k - 3;
        if (u >= 0 && !(u & 1) && (u >> 1) < Win) { ixs[nix] = u >> 1; kxs[nix] = k; ++nix; }
    }
    float acc = bias[oc];
    for (int ic = 0; ic < Cin; ++ic) {
        const float* ib = in + ((b * Cin + ic) * Hin) * Win;
        const float* wc = sw + ic * 16;
        for (int a = 0; a < niy; ++a)
            for (int c2 = 0; c2 < nix; ++c2)
                acc = fmaf(ib[iys[a] * Win + ixs[c2]], wc[kys[a] * 4 + kxs[c2]], acc);
    }
    out[((b * Cout + oc) * Hout + oy) * Wout + ox] = fmaxf(acc, 0.0f);
}

// ---------------------------------------------------------------------------
// transposed conv K=5 stride=2 VALID + sigmoid (pad_a = 4).  w: (Cout,Cin,5,5)
__global__ void deconv5s2_sigmoid_kernel(const float* __restrict__ in, const float* __restrict__ w,
                                         const float* __restrict__ bias, float* __restrict__ out,
                                         int Cin, int Hin, int Win, int Hout, int Wout)
{
    const int oc = blockIdx.y, b = blockIdx.z, Cout = gridDim.y;
    __shared__ float sw[512];                  // Cin=16 -> 400
    const int nw = Cin * 25;
    for (int i = threadIdx.x; i < nw; i += blockDim.x) sw[i] = w[oc * nw + i];
    __syncthreads();
    const int p = blockIdx.x * blockDim.x + threadIdx.x;
    if (p >= Hout * Wout) return;
    const int oy = p / Wout, ox = p - oy * Wout;
    int iys[3], kys[3], niy = 0;
    int ixs[3], kxs[3], nix = 0;
    #pragma unroll
    for (int k = 0; k < 5; ++k) {
        int t = oy + k - 4;
        if (t >= 0 && !(t & 1) && (t >> 1) < Hin) { iys[niy] = t >> 1; kys[niy] = k; ++niy; }
        int u = ox + k - 4;
        if (u >= 0 && !(u & 1) && (u >> 1) < Win) { ixs[nix] = u >> 1; kxs[nix] = k; ++nix; }
    }
    float acc = bias[oc];
    for (int ic = 0; ic < Cin; ++ic) {
        const float* ib = in + ((b * Cin + ic) * Hin) * Win;
        const float* wc = sw + ic * 25;
        for (int a = 0; a < niy; ++a)
            for (int c2 = 0; c2 < nix; ++c2)
                acc = fmaf(ib[iys[a] * Win + ixs[c2]], wc[kys[a] * 5 + kxs[c2]], acc);
    }
    out[((b * Cout + oc) * Hout + oy) * Wout + ox] = 1.0f / (1.0f + expf(-acc));
}

// ---------------------------------------------------------------------------
// per-sample xcorr on a CHUNK of samples: blockIdx.x = sample within chunk.
// f: (nb,64,30,30), af: (64,14,14), out: (nb,289)
__global__ void xcorr_kernel(const float* __restrict__ f, const float* __restrict__ af,
                             float* __restrict__ out)
{
    __shared__ float s_af[64 * 196];           // 50176 B
    const int b = blockIdx.x;
    for (int i = threadIdx.x; i < 64 * 196; i += blockDim.x) s_af[i] = af[i];
    __syncthreads();
    const int p = threadIdx.x;
    if (p >= 289) return;
    const int oy = p / 17, ox = p - oy * 17;
    const float* fb = f + (b * 64) * 900 + oy * 30 + ox;
    float acc = 0.0f;
    for (int c = 0; c < 64; ++c) {
        const float* fc = fb + c * 900;
        const float* ac = s_af + c * 196;
        #pragma unroll
        for (int ky = 0; ky < 14; ++ky) {
            const float* fr = fc + ky * 30;
            const float* ar = ac + ky * 14;
            #pragma unroll
            for (int kx = 0; kx < 14; ++kx)
                acc = fmaf(fr[kx], ar[kx], acc);
        }
    }
    out[b * 289 + p] = acc;
}

// ---------------------------------------------------------------------------
extern "C" void kernel_launch(void* const* d_in, const int* in_sizes, int n_in,
                              void* d_out, int out_size, void* d_ws, size_t ws_size,
                              hipStream_t stream)
{
    const float* pos         = (const float*)d_in[0];
    const float* neg         = (const float*)d_in[1];
    const float* pos_crop    = (const float*)d_in[2];
    const float* eps         = (const float*)d_in[3];
    const float* anchor_crop = (const float*)d_in[4];
    const float* ew1 = (const float*)d_in[5];  const float* eb1 = (const float*)d_in[6];
    const float* ew2 = (const float*)d_in[7];  const float* eb2 = (const float*)d_in[8];
    const float* ew3 = (const float*)d_in[9];  const float* eb3 = (const float*)d_in[10];
    const float* mw  = (const float*)d_in[11]; const float* mb  = (const float*)d_in[12];
    const float* lw  = (const float*)d_in[13]; const float* lb  = (const float*)d_in[14];
    const float* dw0 = (const float*)d_in[15]; const float* db0 = (const float*)d_in[16];
    const float* dw1 = (const float*)d_in[17]; const float* db1 = (const float*)d_in[18];
    const float* dw2 = (const float*)d_in[19]; const float* db2 = (const float*)d_in[20];
    const float* dw3 = (const float*)d_in[21]; const float* db3 = (const float*)d_in[22];

    float* out = (float*)d_out;
    float* ws  = (float*)d_ws;

    // output offsets (floats): anchor, cxp, cxn, recon, mu, logvar
    float* o_anchor = out;
    float* o_cxp    = out + 3096768;
    float* o_cxn    = out + 3115264;
    float* o_recon  = out + 3133760;
    float* o_mu     = out + 6230528;
    float* o_lv     = out + 6631936;

    // ---- workspace: 12,544 (AF) + arena 3,246,592 = 3,259,136 floats (13.0 MB)
    // Arena regions are reused across phases; liveness verified per phase.
    float* AF = ws;                 // anchor features 64*14*14, persistent
    float* A  = ws + 12544;         // arena

    // Phase A (anchor enc, B=1): AH1 [0,123008), AH2 [123008,180608)
    float* AH1 = A;
    float* AH2 = A + 123008;
    // Phase B (VAE): E1 [0,984064) 8*32*62*62 ; E2 [984064,1444864) 8*64*30*30 ;
    //                CH3 [1444864,2247680) 64*64*14*14
    float* E1  = A;
    float* E2  = A + 984064;
    float* CH3 = A + 1444864;
    //        head/decoder: Z [0,401408) ; D0 [401408,1204224) ; D1 [1204224,3047424) ;
    //        D2c (16-sample chunk, 16*16*62*62=984064) reuses [0,984064) after Z/D0 dead
    float* Z   = A;
    float* D0  = A + 401408;
    float* D1  = A + 1204224;
    float* D2c = A;
    // Phase C (branches, 4-sample chunks): F1 [0,2032128) 4*32*126*126 ;
    //        F2 [2032128,3016192) 4*64*62*62 ; F3 [3016192,3246592) 4*64*30*30
    float* F1 = A;
    float* F2 = A + 2032128;
    float* F3 = A + 3016192;

    // 1) anchor output = broadcast input
    bcast_anchor_kernel<<<dim3(DIVUP(48387,256), 64), 256, 0, stream>>>(anchor_crop, o_anchor);

    // 2) Phase A: anchor encoder, B=1 (anchor identical across batch)
    conv4s2_relu_kernel<<<dim3(16, 32, 1), 256, 0, stream>>>(anchor_crop, ew1, eb1, AH1, 3, 127, 127, 62, 62);
    conv4s2_relu_kernel<<<dim3(4, 64, 1), 256, 0, stream>>>(AH1, ew2, eb2, AH2, 32, 62, 62, 30, 30);
    conv4s2_relu_kernel<<<dim3(1, 64, 1), 256, 0, stream>>>(AH2, ew3, eb3, AF, 64, 30, 30, 14, 14);

    // 3) Phase B: VAE encoder on pos_crop, 8-sample chunks -> CH3
    for (int c = 0; c < 8; ++c) {
        const float* inp = pos_crop + (size_t)c * 8 * 48387;
        conv4s2_relu_kernel<<<dim3(16, 32, 8), 256, 0, stream>>>(inp, ew1, eb1, E1, 3, 127, 127, 62, 62);
        conv4s2_relu_kernel<<<dim3(4, 64, 8), 256, 0, stream>>>(E1, ew2, eb2, E2, 32, 62, 62, 30, 30);
        conv4s2_relu_kernel<<<dim3(1, 64, 8), 256, 0, stream>>>(E2, ew3, eb3, CH3 + (size_t)c * 8 * 12544, 64, 30, 30, 14, 14);
    }
    //    head + decoder
    vae_head_kernel<<<1568, 256, 0, stream>>>(CH3, mw, mb, lw, lb, eps, o_mu, o_lv, Z);
    conv1x1_relu_kernel<<<3136, 256, 0, stream>>>(Z, dw0, db0, D0, 32, 64, 196, 64*64*196);
    deconv4s2_relu_kernel<<<dim3(4, 32, 64), 256, 0, stream>>>(D0, dw1, db1, D1, 64, 14, 14, 30, 30);
    for (int c = 0; c < 4; ++c) {   // 16-sample chunks for deconv2+deconv3
        deconv4s2_relu_kernel<<<dim3(16, 16, 16), 256, 0, stream>>>(D1 + (size_t)c * 16 * 28800, dw2, db2, D2c, 32, 30, 30, 62, 62);
        // 127*127 = 16129 -> DIVUP = 64 tiles (63 misses pixel (126,126) -- round-2 bug)
        deconv5s2_sigmoid_kernel<<<dim3(64, 3, 16), 256, 0, stream>>>(D2c, dw3, db3, o_recon + (size_t)c * 16 * 48387, 16, 62, 62, 127, 127);
    }

    // 4) Phase C: siamese branches, 4-sample chunks, xcorr fused per chunk
    for (int br = 0; br < 2; ++br) {
        const float* src  = br ? neg : pos;
        float*       o_cx = br ? o_cxn : o_cxp;
        for (int c = 0; c < 16; ++c) {
            const float* inp = src + (size_t)c * 4 * 195075;
            conv4s2_relu_kernel<<<dim3(63, 32, 4), 256, 0, stream>>>(inp, ew1, eb1, F1, 3, 255, 255, 126, 126);
            conv4s2_relu_kernel<<<dim3(16, 64, 4), 256, 0, stream>>>(F1, ew2, eb2, F2, 32, 126, 126, 62, 62);
            conv4s2_relu_kernel<<<dim3(4, 64, 4), 256, 0, stream>>>(F2, ew3, eb3, F3, 64, 62, 62, 30, 30);
            xcorr_kernel<<<4, 320, 0, stream>>>(F3, AF, o_cx + (size_t)c * 4 * 289);
        }
    }
}

// Round 4
// 3431.379 us; speedup vs baseline: 2.8607x; 2.8607x over previous
//
#include <hip/hip_runtime.h>

#define DIVUP(a,b) (((a)+(b)-1)/(b))

// ---------------------------------------------------------------------------
// anchor broadcast: out[b][c][y][x] = anchor_crop[c][y][x]
__global__ void bcast_anchor_kernel(const float* __restrict__ a, float* __restrict__ out) {
    int i = blockIdx.x * 256 + threadIdx.x;   // over 3*127*127 = 48387
    int b = blockIdx.y;
    if (i < 48387) out[b * 48387 + i] = a[i];
}

// ---------------------------------------------------------------------------
// conv K=4 stride=2 VALID + ReLU, register-tiled: 4 ocs x 4 x-pixels per thread.
// w: (Cout,Cin,4,4).  grid: (ceil(Hout*ceil(Wout/4)/256), Cout/4, B), 256 thr.
// Tail x-tiles shift left (overlap threads write identical values -> benign).
__global__ void conv4s2x4_relu_kernel(const float* __restrict__ in, const float* __restrict__ w,
                                      const float* __restrict__ bias, float* __restrict__ out,
                                      int Cin, int Hin, int Win, int Hout, int Wout)
{
    const int ocg = blockIdx.y, b = blockIdx.z, Cout = gridDim.y * 4;
    __shared__ float sw[4096];                 // 4 ocs * Cin(<=64) * 16
    const int nw = 4 * Cin * 16;
    const float* wb = w + (size_t)ocg * nw;
    for (int i = threadIdx.x; i < nw; i += 256) sw[i] = wb[i];
    __syncthreads();
    const int TX = (Wout + 3) >> 2;
    const int t  = blockIdx.x * 256 + threadIdx.x;
    if (t >= Hout * TX) return;
    const int oy = t / TX, tx = t - oy * TX;
    int ox0 = tx * 4; if (ox0 > Wout - 4) ox0 = Wout - 4;

    const float* ip = in + ((size_t)(b * Cin) * Hin + 2 * oy) * Win + 2 * ox0;
    float acc[4][4];
    #pragma unroll
    for (int o = 0; o < 4; ++o) {
        float z = bias[ocg * 4 + o];
        acc[o][0] = z; acc[o][1] = z; acc[o][2] = z; acc[o][3] = z;
    }
    for (int ic = 0; ic < Cin; ++ic) {
        const float* r = ip + (size_t)ic * Hin * Win;
        #pragma unroll
        for (int ky = 0; ky < 4; ++ky) {
            const float* rr = r + ky * Win;
            float x0 = rr[0], x1 = rr[1], x2 = rr[2], x3 = rr[3], x4 = rr[4],
                  x5 = rr[5], x6 = rr[6], x7 = rr[7], x8 = rr[8], x9 = rr[9];
            #pragma unroll
            for (int o = 0; o < 4; ++o) {
                const float* wk = sw + ((o * Cin + ic) * 4 + ky) * 4;
                float w0 = wk[0], w1 = wk[1], w2 = wk[2], w3 = wk[3];
                acc[o][0] = fmaf(x0, w0, fmaf(x1, w1, fmaf(x2, w2, fmaf(x3, w3, acc[o][0]))));
                acc[o][1] = fmaf(x2, w0, fmaf(x3, w1, fmaf(x4, w2, fmaf(x5, w3, acc[o][1]))));
                acc[o][2] = fmaf(x4, w0, fmaf(x5, w1, fmaf(x6, w2, fmaf(x7, w3, acc[o][2]))));
                acc[o][3] = fmaf(x6, w0, fmaf(x7, w1, fmaf(x8, w2, fmaf(x9, w3, acc[o][3]))));
            }
        }
    }
    float* op = out + (((size_t)b * Cout + ocg * 4) * Hout + oy) * Wout + ox0;
    #pragma unroll
    for (int o = 0; o < 4; ++o) {
        float* q = op + (size_t)o * Hout * Wout;
        q[0] = fmaxf(acc[o][0], 0.0f); q[1] = fmaxf(acc[o][1], 0.0f);
        q[2] = fmaxf(acc[o][2], 0.0f); q[3] = fmaxf(acc[o][3], 0.0f);
    }
}

// ---------------------------------------------------------------------------
// fused VAE head: mu = h*mw+mb, logvar = h*lw+lb, z = mu + eps*exp(0.5*logvar)
__global__ void vae_head_kernel(const float* __restrict__ h, const float* __restrict__ mw,
                                const float* __restrict__ mb, const float* __restrict__ lw,
                                const float* __restrict__ lb, const float* __restrict__ eps,
                                float* __restrict__ mu_out, float* __restrict__ lv_out,
                                float* __restrict__ z_out)
{
    const int idx = blockIdx.x * 256 + threadIdx.x;   // over 64*32*196
    if (idx >= 64 * 32 * 196) return;
    const int p  = idx % 196;
    const int oc = (idx / 196) % 32;
    const int b  = idx / (196 * 32);
    const float* hb = h + (b * 64) * 196 + p;
    float am = mb[oc], al = lb[oc];
    for (int ic = 0; ic < 64; ++ic) {
        float hv = hb[ic * 196];
        am = fmaf(hv, mw[oc * 64 + ic], am);
        al = fmaf(hv, lw[oc * 64 + ic], al);
    }
    mu_out[idx] = am;
    lv_out[idx] = al;
    z_out[idx]  = fmaf(eps[idx], expf(0.5f * al), am);
}

// ---------------------------------------------------------------------------
// 1x1 conv + ReLU.  w: (Cout,Cin)
__global__ void conv1x1_relu_kernel(const float* __restrict__ in, const float* __restrict__ w,
                                    const float* __restrict__ bias, float* __restrict__ out,
                                    int Cin, int Cout, int HW, int total)
{
    const int idx = blockIdx.x * 256 + threadIdx.x;
    if (idx >= total) return;
    const int p  = idx % HW;
    const int oc = (idx / HW) % Cout;
    const int b  = idx / (HW * Cout);
    const float* ib = in + (b * Cin) * HW + p;
    float acc = bias[oc];
    for (int ic = 0; ic < Cin; ++ic) acc = fmaf(ib[ic * HW], w[oc * Cin + ic], acc);
    out[idx] = fmaxf(acc, 0.0f);
}

// ---------------------------------------------------------------------------
// transposed conv K=4 s=2 VALID + ReLU, 4-oc-tiled, taps hoisted & padded to 4.
// (JAX conv_transpose: no flip, pad=3 -> tap iy=(oy+ky-3)/2 when even & in range;
//  parity gives <=2 ky x <=2 kx = <=4 taps, >=1 always.)
// w: (Cout,Cin,4,4).  grid: (ceil(Hout*Wout/256), Cout/4, B)
__global__ void deconv4s2x4_relu_kernel(const float* __restrict__ in, const float* __restrict__ w,
                                        const float* __restrict__ bias, float* __restrict__ out,
                                        int Cin, int Hin, int Win, int Hout, int Wout)
{
    const int ocg = blockIdx.y, b = blockIdx.z, Cout = gridDim.y * 4;
    __shared__ float sw[4096];
    const int nw = 4 * Cin * 16;
    const float* wb = w + (size_t)ocg * nw;
    for (int i = threadIdx.x; i < nw; i += 256) sw[i] = wb[i];
    __syncthreads();
    const int p = blockIdx.x * 256 + threadIdx.x;
    if (p >= Hout * Wout) return;
    const int oy = p / Wout, ox = p - oy * Wout;
    int off[4], wo[4], nt = 0;
    #pragma unroll
    for (int ky = 0; ky < 4; ++ky) {
        int t = oy + ky - 3;
        if (t < 0 || (t & 1) || (t >> 1) >= Hin) continue;
        #pragma unroll
        for (int kx = 0; kx < 4; ++kx) {
            int u = ox + kx - 3;
            if (u < 0 || (u & 1) || (u >> 1) >= Win) continue;
            off[nt] = (t >> 1) * Win + (u >> 1);
            wo[nt]  = ky * 4 + kx;
            ++nt;
        }
    }
    #pragma unroll
    for (int j = 1; j < 4; ++j) if (j >= nt) { off[j] = off[0]; wo[j] = wo[0]; }
    const bool m1 = 1 < nt, m2 = 2 < nt, m3 = 3 < nt;
    float a0 = bias[ocg*4+0], a1 = bias[ocg*4+1], a2 = bias[ocg*4+2], a3 = bias[ocg*4+3];
    const float* ib = in + (size_t)(b * Cin) * Hin * Win;
    for (int ic = 0; ic < Cin; ++ic) {
        const float* base = ib + (size_t)ic * Hin * Win;
        float x0 = base[off[0]];
        float x1 = m1 ? base[off[1]] : 0.0f;
        float x2 = m2 ? base[off[2]] : 0.0f;
        float x3 = m3 ? base[off[3]] : 0.0f;
        const float* wc0 = sw + (0 * Cin + ic) * 16;
        const float* wc1 = sw + (1 * Cin + ic) * 16;
        const float* wc2 = sw + (2 * Cin + ic) * 16;
        const float* wc3 = sw + (3 * Cin + ic) * 16;
        a0 = fmaf(x0, wc0[wo[0]], fmaf(x1, wc0[wo[1]], fmaf(x2, wc0[wo[2]], fmaf(x3, wc0[wo[3]], a0))));
        a1 = fmaf(x0, wc1[wo[0]], fmaf(x1, wc1[wo[1]], fmaf(x2, wc1[wo[2]], fmaf(x3, wc1[wo[3]], a1))));
        a2 = fmaf(x0, wc2[wo[0]], fmaf(x1, wc2[wo[1]], fmaf(x2, wc2[wo[2]], fmaf(x3, wc2[wo[3]], a2))));
        a3 = fmaf(x0, wc3[wo[0]], fmaf(x1, wc3[wo[1]], fmaf(x2, wc3[wo[2]], fmaf(x3, wc3[wo[3]], a3))));
    }
    float* op = out + (((size_t)b * Cout + ocg * 4) * Hout + oy) * Wout + ox;
    const size_t st = (size_t)Hout * Wout;
    op[0] = fmaxf(a0, 0.0f); op[st] = fmaxf(a1, 0.0f);
    op[2*st] = fmaxf(a2, 0.0f); op[3*st] = fmaxf(a3, 0.0f);
}

// ---------------------------------------------------------------------------
// transposed conv K=5 stride=2 VALID + sigmoid (pad_a = 4).  w: (Cout,Cin,5,5)
__global__ void deconv5s2_sigmoid_kernel(const float* __restrict__ in, const float* __restrict__ w,
                                         const float* __restrict__ bias, float* __restrict__ out,
                                         int Cin, int Hin, int Win, int Hout, int Wout)
{
    const int oc = blockIdx.y, b = blockIdx.z, Cout = gridDim.y;
    __shared__ float sw[512];                  // Cin=16 -> 400
    const int nw = Cin * 25;
    for (int i = threadIdx.x; i < nw; i += blockDim.x) sw[i] = w[oc * nw + i];
    __syncthreads();
    const int p = blockIdx.x * blockDim.x + threadIdx.x;
    if (p >= Hout * Wout) return;
    const int oy = p / Wout, ox = p - oy * Wout;
    int iys[3], kys[3], niy = 0;
    int ixs[3], kxs[3], nix = 0;
    #pragma unroll
    for (int k = 0; k < 5; ++k) {
        int t = oy + k - 4;
        if (t >= 0 && !(t & 1) && (t >> 1) < Hin) { iys[niy] = t >> 1; kys[niy] = k; ++niy; }
        int u = ox + k - 4;
        if (u >= 0 && !(u & 1) && (u >> 1) < Win) { ixs[nix] = u >> 1; kxs[nix] = k; ++nix; }
    }
    float acc = bias[oc];
    for (int ic = 0; ic < Cin; ++ic) {
        const float* ib = in + ((b * Cin + ic) * Hin) * Win;
        const float* wc = sw + ic * 25;
        for (int a = 0; a < niy; ++a)
            for (int c2 = 0; c2 < nix; ++c2)
                acc = fmaf(ib[iys[a] * Win + ixs[c2]], wc[kys[a] * 5 + kxs[c2]], acc);
    }
    out[((b * Cout + oc) * Hout + oy) * Wout + ox] = 1.0f / (1.0f + expf(-acc));
}

// ---------------------------------------------------------------------------
// per-sample xcorr, 8-way channel split: grid (nb, 8), 320 thr.
// f: (nb,64,30,30), af: (64,14,14), out[b*289+p] += partial (atomic; pre-zeroed)
__global__ void xcorr_split_kernel(const float* __restrict__ f, const float* __restrict__ af,
                                   float* __restrict__ out)
{
    __shared__ float s_af[8 * 196];
    const int b = blockIdx.x, g = blockIdx.y;
    for (int i = threadIdx.x; i < 8 * 196; i += 320) s_af[i] = af[g * 8 * 196 + i];
    __syncthreads();
    const int p = threadIdx.x;
    if (p >= 289) return;
    const int oy = p / 17, ox = p - oy * 17;
    const float* fb = f + ((size_t)b * 64 + g * 8) * 900 + oy * 30 + ox;
    float acc = 0.0f;
    for (int c = 0; c < 8; ++c) {
        const float* fc = fb + c * 900;
        const float* ac = s_af + c * 196;
        #pragma unroll
        for (int ky = 0; ky < 14; ++ky) {
            const float* fr = fc + ky * 30;
            const float* ar = ac + ky * 14;
            #pragma unroll
            for (int kx = 0; kx < 14; ++kx)
                acc = fmaf(fr[kx], ar[kx], acc);
        }
    }
    atomicAdd(&out[b * 289 + p], acc);
}

// ---------------------------------------------------------------------------
extern "C" void kernel_launch(void* const* d_in, const int* in_sizes, int n_in,
                              void* d_out, int out_size, void* d_ws, size_t ws_size,
                              hipStream_t stream)
{
    const float* pos         = (const float*)d_in[0];
    const float* neg         = (const float*)d_in[1];
    const float* pos_crop    = (const float*)d_in[2];
    const float* eps         = (const float*)d_in[3];
    const float* anchor_crop = (const float*)d_in[4];
    const float* ew1 = (const float*)d_in[5];  const float* eb1 = (const float*)d_in[6];
    const float* ew2 = (const float*)d_in[7];  const float* eb2 = (const float*)d_in[8];
    const float* ew3 = (const float*)d_in[9];  const float* eb3 = (const float*)d_in[10];
    const float* mw  = (const float*)d_in[11]; const float* mb  = (const float*)d_in[12];
    const float* lw  = (const float*)d_in[13]; const float* lb  = (const float*)d_in[14];
    const float* dw0 = (const float*)d_in[15]; const float* db0 = (const float*)d_in[16];
    const float* dw1 = (const float*)d_in[17]; const float* db1 = (const float*)d_in[18];
    const float* dw2 = (const float*)d_in[19]; const float* db2 = (const float*)d_in[20];
    const float* dw3 = (const float*)d_in[21]; const float* db3 = (const float*)d_in[22];

    float* out = (float*)d_out;
    float* ws  = (float*)d_ws;

    // output offsets (floats): anchor, cxp, cxn, recon, mu, logvar
    float* o_anchor = out;
    float* o_cxp    = out + 3096768;
    float* o_cxn    = out + 3115264;
    float* o_recon  = out + 3133760;
    float* o_mu     = out + 6230528;
    float* o_lv     = out + 6631936;

    // ---- workspace: AF (12544) + arena; min footprint 13 MB (proven round 3)
    float* AF = ws;                 // anchor features 64*14*14, persistent
    float* A  = ws + 12544;

    // Phase A (anchor enc, B=1)
    float* AH1 = A;                 // 32*62*62
    float* AH2 = A + 123008;        // 64*30*30
    // Phase B (VAE, 8-sample chunks): fixed known-good offsets
    float* E1  = A;                 // 8*32*62*62
    float* E2  = A + 984064;        // 8*64*30*30
    float* CH3 = A + 1444864;       // 64*64*14*14
    float* Z   = A;                 // 64*32*14*14
    float* D0  = A + 401408;        // 64*64*14*14
    float* D1  = A + 1204224;       // 64*32*30*30
    float* D2c = A;                 // 16*16*62*62 (chunk)
    // Phase C (branches): chunk CB chosen from ws_size; per-sample 811584 floats
    long nf = (long)(ws_size / 4);
    long arena = nf - 12544;
    int CB = 4;
    if (16L * 811584 <= arena) CB = 16;
    else if (8L * 811584 <= arena) CB = 8;
    float* F1 = A;                          // CB*32*126*126
    float* F2 = A + (size_t)CB * 508032;    // CB*64*62*62
    float* F3 = F2 + (size_t)CB * 245952;   // CB*64*30*30

    // 1) anchor output = broadcast input
    bcast_anchor_kernel<<<dim3(189, 64), 256, 0, stream>>>(anchor_crop, o_anchor);

    // 2) Phase A: anchor encoder, B=1 (anchor identical across batch)
    conv4s2x4_relu_kernel<<<dim3(4, 8, 1), 256, 0, stream>>>(anchor_crop, ew1, eb1, AH1, 3, 127, 127, 62, 62);
    conv4s2x4_relu_kernel<<<dim3(1, 16, 1), 256, 0, stream>>>(AH1, ew2, eb2, AH2, 32, 62, 62, 30, 30);
    conv4s2x4_relu_kernel<<<dim3(1, 16, 1), 256, 0, stream>>>(AH2, ew3, eb3, AF, 64, 30, 30, 14, 14);

    // 3) Phase B: VAE encoder on pos_crop, 8-sample chunks -> CH3
    for (int c = 0; c < 8; ++c) {
        const float* inp = pos_crop + (size_t)c * 8 * 48387;
        conv4s2x4_relu_kernel<<<dim3(4, 8, 8), 256, 0, stream>>>(inp, ew1, eb1, E1, 3, 127, 127, 62, 62);
        conv4s2x4_relu_kernel<<<dim3(1, 16, 8), 256, 0, stream>>>(E1, ew2, eb2, E2, 32, 62, 62, 30, 30);
        conv4s2x4_relu_kernel<<<dim3(1, 16, 8), 256, 0, stream>>>(E2, ew3, eb3, CH3 + (size_t)c * 8 * 12544, 64, 30, 30, 14, 14);
    }
    //    head + decoder
    vae_head_kernel<<<1568, 256, 0, stream>>>(CH3, mw, mb, lw, lb, eps, o_mu, o_lv, Z);
    conv1x1_relu_kernel<<<3136, 256, 0, stream>>>(Z, dw0, db0, D0, 32, 64, 196, 64*64*196);
    deconv4s2x4_relu_kernel<<<dim3(4, 8, 64), 256, 0, stream>>>(D0, dw1, db1, D1, 64, 14, 14, 30, 30);
    for (int c = 0; c < 4; ++c) {   // 16-sample chunks for deconv2+deconv3
        deconv4s2x4_relu_kernel<<<dim3(16, 4, 16), 256, 0, stream>>>(D1 + (size_t)c * 16 * 28800, dw2, db2, D2c, 32, 30, 30, 62, 62);
        deconv5s2_sigmoid_kernel<<<dim3(64, 3, 16), 256, 0, stream>>>(D2c, dw3, db3, o_recon + (size_t)c * 16 * 48387, 16, 62, 62, 127, 127);
    }

    // 4) Phase C: siamese branches, merged pos+neg stream, CB-sample chunks
    hipMemsetAsync(o_cxp, 0, 2 * 18496 * sizeof(float), stream);  // cxp+cxn contiguous
    const int nchunks = 128 / CB;
    for (int c = 0; c < nchunks; ++c) {
        const int s0 = c * CB;   // virtual sample index; CB divides 64 -> no straddle
        const float* inp  = (s0 < 64) ? pos + (size_t)s0 * 195075 : neg + (size_t)(s0 - 64) * 195075;
        float*       o_cx = (s0 < 64) ? o_cxp + (size_t)s0 * 289  : o_cxn + (size_t)(s0 - 64) * 289;
        conv4s2x4_relu_kernel<<<dim3(16, 8, CB), 256, 0, stream>>>(inp, ew1, eb1, F1, 3, 255, 255, 126, 126);
        conv4s2x4_relu_kernel<<<dim3(4, 16, CB), 256, 0, stream>>>(F1, ew2, eb2, F2, 32, 126, 126, 62, 62);
        conv4s2x4_relu_kernel<<<dim3(1, 16, CB), 256, 0, stream>>>(F2, ew3, eb3, F3, 64, 62, 62, 30, 30);
        xcorr_split_kernel<<<dim3(CB, 8), 320, 0, stream>>>(F3, AF, o_cx);
    }
}